// Round 1
// baseline (96.692 us; speedup 1.0000x reference)
//
#include <hip/hip_runtime.h>

#define NN   2048
#define IN   64
#define HID  32
#define OUTD 16

// Dataflow: colsum(x) -> agg1 -> h1=relu(x@W1+agg1) -> colsum(h1) -> agg2
//           -> out = h1@W2 + agg2
// Two global reductions, but both reduce L2-resident data (x: 512 KB,
// h1: 256 KB). Instead of a separate reduction kernel + partials round-trip
// (previous 3-kernel scheme), every block computes the full column-sum
// redundantly from L2: 64 blocks x 512 KB = 32 MB L2 traffic ~ 1 us,
// cheaper than an extra dispatch + inter-kernel gap.  => 2 kernels.
//
// ws layout (floats) — write-before-read only (0xAA poison harmless):
//   [0, 2048*32) : h1, row-major (written by kA, read by kB)

// ---------------------------------------------------------------- kA -------
__global__ __launch_bounds__(256) void kA_layer1(const float* __restrict__ x,
                                                 const float* __restrict__ bases1,
                                                 const float* __restrict__ coeff1,
                                                 const float* __restrict__ loop_w1,
                                                 const float* __restrict__ bias1,
                                                 float* __restrict__ ws) {
    __shared__ float  w1sh[IN * HID];   // 8 KB
    __shared__ float  xsh[32 * IN];     // 8 KB
    __shared__ float4 red4[256];        // 4 KB
    __shared__ float  red[256];         // 1 KB
    __shared__ float  s0sh[IN];
    __shared__ float  agg1sh[HID];
    const int tid = threadIdx.x, b = blockIdx.x;   // 64 blocks x 32 rows

    // stage own x tile + w1 (float4, 2/thread each, issue early)
    const float4* x4  = (const float4*)(x + b * 32 * IN);
    const float4* w14 = (const float4*)loop_w1;
    float4 xa = x4[tid], xb4 = x4[tid + 256];
    float4 wa = w14[tid], wb = w14[tid + 256];

    // block-redundant full colsum of x (L2-served after first toucher).
    // row = 16 float4; lanes 0..63 = 4 rows x 16 quads = 1 KB contiguous.
    {
        const int q = tid & 15, rg = tid >> 4;     // quad-col, row-group of 16
        const float4* xg = (const float4*)x;
        float4 s = {0.f, 0.f, 0.f, 0.f};
#pragma unroll 8
        for (int r = rg; r < NN; r += 16) {
            float4 v = xg[r * 16 + q];
            s.x += v.x; s.y += v.y; s.z += v.z; s.w += v.w;
        }
        ((float4*)xsh)[tid] = xa; ((float4*)xsh)[tid + 256] = xb4;
        ((float4*)w1sh)[tid] = wa; ((float4*)w1sh)[tid + 256] = wb;
        red4[tid] = s;
    }
    __syncthreads();
    if (tid < 16) {                                // quad-col tid: sum 16 row-groups
        float4 t = {0.f, 0.f, 0.f, 0.f};
#pragma unroll
        for (int g = 0; g < 16; ++g) {
            float4 v = red4[g * 16 + tid];
            t.x += v.x; t.y += v.y; t.z += v.z; t.w += v.w;
        }
        s0sh[tid * 4 + 0] = t.x; s0sh[tid * 4 + 1] = t.y;
        s0sh[tid * 4 + 2] = t.z; s0sh[tid * 4 + 3] = t.w;
    }
    __syncthreads();

    // agg1[h] = bias1[h] + c1 * sum_k s0[k]*bases1[k*HID+h]
    {
        const int h = tid & 31, seg = tid >> 5;
        float p = 0.f;
#pragma unroll
        for (int k = 0; k < 8; ++k)
            p += s0sh[seg * 8 + k] * bases1[(seg * 8 + k) * HID + h];
        red[tid] = p;
        __syncthreads();
        if (tid < HID) {
            float t = 0.f;
#pragma unroll
            for (int g = 0; g < 8; ++g) t += red[g * 32 + tid];
            agg1sh[tid] = bias1[tid] + coeff1[0] * t;
        }
    }
    __syncthreads();

    // h1 for 32 rows: thread = (h = tid&31, rgrp = tid>>5), rows rgrp + {0,8,16,24}
    {
        const int h = tid & 31, rgrp = tid >> 5;
        const float agg1v = agg1sh[h];
        float a0 = agg1v, a1 = agg1v, a2 = agg1v, a3 = agg1v;
#pragma unroll
        for (int k = 0; k < IN; ++k) {
            const float w = w1sh[k * HID + h];     // broadcast within wave
            a0 += xsh[(rgrp +  0) * IN + k] * w;
            a1 += xsh[(rgrp +  8) * IN + k] * w;
            a2 += xsh[(rgrp + 16) * IN + k] * w;
            a3 += xsh[(rgrp + 24) * IN + k] * w;
        }
        a0 = fmaxf(a0, 0.f); a1 = fmaxf(a1, 0.f);
        a2 = fmaxf(a2, 0.f); a3 = fmaxf(a3, 0.f);
        float* h1b = ws + b * 32 * HID;
        h1b[(rgrp +  0) * HID + h] = a0;
        h1b[(rgrp +  8) * HID + h] = a1;
        h1b[(rgrp + 16) * HID + h] = a2;
        h1b[(rgrp + 24) * HID + h] = a3;
    }
}

// ---------------------------------------------------------------- kB -------
__global__ __launch_bounds__(256) void kB_layer2(const float* __restrict__ bases2,
                                                 const float* __restrict__ coeff2,
                                                 const float* __restrict__ loop_w2,
                                                 const float* __restrict__ bias2,
                                                 const float* __restrict__ ws,
                                                 float* __restrict__ out) {
    __shared__ float  w2sh[HID * OUTD];     // loop_w2, 2 KB
    __shared__ float  w2csh[HID * OUTD];    // sum_r coeff2[0,r]*bases2[r], 2 KB
    __shared__ float  h1sh[32 * 36];        // own 32 rows, stride 36 (f4-aligned pad)
    __shared__ float4 red4[256];            // 4 KB
    __shared__ float  s1sh[HID];
    __shared__ float  agg2sh[OUTD];
    const int tid = threadIdx.x, b = blockIdx.x;   // 64 blocks x 32 rows

    // stage weights + combined basis (2 elements/thread)
    {
        const float c20 = coeff2[0], c21 = coeff2[1], c22 = coeff2[2], c23 = coeff2[3];
#pragma unroll
        for (int j = 0; j < 2; ++j) {
            const int i = tid + j * 256;
            w2sh[i]  = loop_w2[i];
            w2csh[i] = c20 * bases2[i]        + c21 * bases2[512 + i] +
                       c22 * bases2[1024 + i] + c23 * bases2[1536 + i];
        }
    }
    // own h1 tile: 1024 floats, 1 float4/thread, padded-stride LDS write
    {
        const float4 v = ((const float4*)(ws + b * 32 * HID))[tid];
        const int row = tid >> 3, q = tid & 7;
        ((float4*)&h1sh[row * 36])[q] = v;
    }
    // block-redundant full colsum of h1 (L2-served).
    // row = 8 float4; lanes 0..63 = 8 rows x 8 quads = 1 KB contiguous.
    {
        const int q = tid & 7, rg = tid >> 3;      // quad-col, row-group of 32
        const float4* hg = (const float4*)ws;
        float4 s = {0.f, 0.f, 0.f, 0.f};
#pragma unroll 8
        for (int r = rg; r < NN; r += 32) {
            float4 v = hg[r * 8 + q];
            s.x += v.x; s.y += v.y; s.z += v.z; s.w += v.w;
        }
        red4[tid] = s;
    }
    __syncthreads();
    if (tid < 8) {                                 // quad-col tid: sum 32 row-groups
        float4 t = {0.f, 0.f, 0.f, 0.f};
#pragma unroll
        for (int g = 0; g < 32; ++g) {
            float4 v = red4[g * 8 + tid];
            t.x += v.x; t.y += v.y; t.z += v.z; t.w += v.w;
        }
        s1sh[tid * 4 + 0] = t.x; s1sh[tid * 4 + 1] = t.y;
        s1sh[tid * 4 + 2] = t.z; s1sh[tid * 4 + 3] = t.w;
    }
    __syncthreads();
    if (tid < OUTD) {
        float s = 0.f;
#pragma unroll
        for (int h = 0; h < HID; ++h) s += s1sh[h] * w2csh[h * OUTD + tid];
        agg2sh[tid] = bias2[tid] + s;
    }
    __syncthreads();

    // out: 32 rows x 16 cols = 512 -> 2/thread, coalesced stores
    {
        const int r0 = tid >> 4, o = tid & 15;
        float acc0 = agg2sh[o], acc1 = agg2sh[o];
#pragma unroll
        for (int h = 0; h < HID; ++h) {
            const float w = w2sh[h * OUTD + o];
            acc0 += h1sh[(r0     ) * 36 + h] * w;
            acc1 += h1sh[(r0 + 16) * 36 + h] * w;
        }
        out[b * 512 + tid]       = acc0;
        out[b * 512 + 256 + tid] = acc1;
    }
}

extern "C" void kernel_launch(void* const* d_in, const int* in_sizes, int n_in,
                              void* d_out, int out_size, void* d_ws, size_t ws_size,
                              hipStream_t stream) {
    const float* x       = (const float*)d_in[0];
    // d_in[1] = adj_matrix: mathematically unused (complete graph w/ self-loops)
    const float* bases1  = (const float*)d_in[2];
    const float* coeff1  = (const float*)d_in[3];
    const float* loop_w1 = (const float*)d_in[4];
    const float* bias1   = (const float*)d_in[5];
    const float* bases2  = (const float*)d_in[6];
    const float* coeff2  = (const float*)d_in[7];
    const float* loop_w2 = (const float*)d_in[8];
    const float* bias2   = (const float*)d_in[9];
    float* out = (float*)d_out;
    float* ws  = (float*)d_ws;

    kA_layer1<<<64, 256, 0, stream>>>(x, bases1, coeff1, loop_w1, bias1, ws);
    kB_layer2<<<64, 256, 0, stream>>>(bases2, coeff2, loop_w2, bias2, ws, out);
}

// Round 2
// 88.349 us; speedup vs baseline: 1.0944x; 1.0944x over previous
//
#include <hip/hip_runtime.h>

#define NN   2048
#define IN   64
#define HID  32
#define OUTD 16

// Dataflow: s0=colsum(x) -> agg1 -> h1=relu(x@W1+agg1) -> s1=colsum(h1)
//           -> out = h1@loop_w2 + (bias2 + s1@W2c)
// Two global reductions => 3 kernels (grid.sync measured slower; block-redundant
// full colsum measured slower, R1: 64-block grid can't hide the L2 latency chain).
//
// Key split: out = h1@loop_w2 + agg2.  The matmul term needs no global info, so
// k2 computes it from in-register h1 and writes `out` directly — h1 NEVER goes
// to global memory.  k3 only reduces the tiny s1 partials and RMW-adds the
// rank-1 agg2 term onto out.
//
// ws layout (floats) — every slot write-before-read (0xAA poison harmless):
//   [S0P, S0P+64*64) : k1 per-block partial colsums of x   (64 blocks x 64)
//   [S1P, S1P+64*32) : k2 per-block partial colsums of h1  (64 blocks x 32)
#define S0P 0
#define S1P 4096

// ---------------------------------------------------------------- k1 -------
__global__ __launch_bounds__(256) void k1_colsum_x(const float* __restrict__ x,
                                                   float* __restrict__ ws) {
    __shared__ float red[256];
    const int tid = threadIdx.x, b = blockIdx.x;   // 64 blocks x 32 rows
    const int col = tid & 63, grp = tid >> 6;      // 4 groups x 8 rows
    const float* xb = x + b * 32 * IN;
    float s = 0.f;
#pragma unroll
    for (int r = 0; r < 8; ++r)                    // 8 independent coalesced loads
        s += xb[(grp * 8 + r) * IN + col];
    red[tid] = s;
    __syncthreads();
    if (tid < 64)
        ws[S0P + b * 64 + tid] = red[tid] + red[tid + 64] + red[tid + 128] + red[tid + 192];
}

// ---------------------------------------------------------------- k2 -------
__global__ __launch_bounds__(256) void k2_layer1(const float* __restrict__ x,
                                                 const float* __restrict__ bases1,
                                                 const float* __restrict__ coeff1,
                                                 const float* __restrict__ loop_w1,
                                                 const float* __restrict__ bias1,
                                                 const float* __restrict__ loop_w2,
                                                 float* __restrict__ ws,
                                                 float* __restrict__ out) {
    __shared__ float w1sh[IN * HID];        // 8 KB
    __shared__ float xsh[32 * IN];          // 8 KB
    __shared__ float w2sh[HID * OUTD];      // 2 KB  (loop_w2)
    __shared__ float h1sh[32 * 33];         // 4.2 KB, +1 pad
    __shared__ float s0sh[IN];
    __shared__ float agg1sh[HID];
    __shared__ float red[256];
    const int tid = threadIdx.x, b = blockIdx.x;   // 64 blocks x 32 rows

    // stage own x tile + w1 + w2 (float4, all independent, issue early)
    const float4* x4  = (const float4*)(x + b * 32 * IN);
    const float4* w14 = (const float4*)loop_w1;
    float4 xa = x4[tid], xb4 = x4[tid + 256];
    float4 wa = w14[tid], wb = w14[tid + 256];
    float4 w2v = {0.f, 0.f, 0.f, 0.f};
    if (tid < 128) w2v = ((const float4*)loop_w2)[tid];

    // reduce s0 partials (64 x 64) — 16 independent L2-hot loads per thread
    {
        const int col = tid & 63, g = tid >> 6;    // g sums blocks 16g..16g+15
        float a0 = 0.f, a1 = 0.f, a2 = 0.f, a3 = 0.f;
#pragma unroll
        for (int k = 0; k < 4; ++k) {
            a0 += ws[S0P + (g * 16 + k     ) * 64 + col];
            a1 += ws[S0P + (g * 16 + 4 + k ) * 64 + col];
            a2 += ws[S0P + (g * 16 + 8 + k ) * 64 + col];
            a3 += ws[S0P + (g * 16 + 12 + k) * 64 + col];
        }
        ((float4*)xsh)[tid] = xa; ((float4*)xsh)[tid + 256] = xb4;
        ((float4*)w1sh)[tid] = wa; ((float4*)w1sh)[tid + 256] = wb;
        if (tid < 128) ((float4*)w2sh)[tid] = w2v;
        red[tid] = a0 + a1 + a2 + a3;
    }
    __syncthreads();
    if (tid < 64)
        s0sh[tid] = red[tid] + red[tid + 64] + red[tid + 128] + red[tid + 192];
    __syncthreads();

    // agg1[h] = bias1[h] + c1 * sum_k s0[k]*bases1[k*HID+h]
    {
        const int h = tid & 31, seg = tid >> 5;
        float p = 0.f;
#pragma unroll
        for (int k = 0; k < 8; ++k)
            p += s0sh[seg * 8 + k] * bases1[(seg * 8 + k) * HID + h];
        red[tid] = p;
        __syncthreads();
        if (tid < HID) {
            float t = 0.f;
#pragma unroll
            for (int g = 0; g < 8; ++g) t += red[g * 32 + tid];
            agg1sh[tid] = bias1[tid] + coeff1[0] * t;
        }
    }
    __syncthreads();

    // h1 for 32 rows: thread = (h = tid&31, rgrp = tid>>5), rows rgrp + {0,8,16,24}
    {
        const int h = tid & 31, rgrp = tid >> 5;
        const float agg1v = agg1sh[h];
        float a0 = agg1v, a1 = agg1v, a2 = agg1v, a3 = agg1v;
#pragma unroll
        for (int k = 0; k < IN; ++k) {
            const float w = w1sh[k * HID + h];     // broadcast within wave
            a0 += xsh[(rgrp +  0) * IN + k] * w;
            a1 += xsh[(rgrp +  8) * IN + k] * w;
            a2 += xsh[(rgrp + 16) * IN + k] * w;
            a3 += xsh[(rgrp + 24) * IN + k] * w;
        }
        a0 = fmaxf(a0, 0.f); a1 = fmaxf(a1, 0.f);
        a2 = fmaxf(a2, 0.f); a3 = fmaxf(a3, 0.f);
        // h1 stays on-chip: LDS only (row*33+h is conflict-free both phases)
        h1sh[(rgrp +  0) * 33 + h] = a0;
        h1sh[(rgrp +  8) * 33 + h] = a1;
        h1sh[(rgrp + 16) * 33 + h] = a2;
        h1sh[(rgrp + 24) * 33 + h] = a3;
        red[tid] = a0 + a1 + a2 + a3;              // partial s1
    }
    __syncthreads();
    if (tid < HID) {
        float t = 0.f;
#pragma unroll
        for (int g = 0; g < 8; ++g) t += red[g * 32 + tid];
        ws[S1P + b * HID + tid] = t;
    }
    // out_part = h1 @ loop_w2, straight to out (agg2 added by k3)
    {
        const int r0 = tid >> 4, o = tid & 15;     // rows r0, r0+16
        float acc0 = 0.f, acc1 = 0.f;
#pragma unroll
        for (int h = 0; h < HID; ++h) {
            const float w = w2sh[h * OUTD + o];    // broadcast within wave
            acc0 += h1sh[(r0     ) * 33 + h] * w;
            acc1 += h1sh[(r0 + 16) * 33 + h] * w;
        }
        out[b * 512 + tid]       = acc0;
        out[b * 512 + 256 + tid] = acc1;
    }
}

// ---------------------------------------------------------------- k3 -------
__global__ __launch_bounds__(256) void k3_finish(const float* __restrict__ bases2,
                                                 const float* __restrict__ coeff2,
                                                 const float* __restrict__ bias2,
                                                 const float* __restrict__ ws,
                                                 float* __restrict__ out) {
    __shared__ float w2csh[HID * OUTD];    // sum_r coeff2[0,r]*bases2[r]
    __shared__ float s1sh[HID];
    __shared__ float agg2sh[OUTD];
    __shared__ float red[256];
    const int tid = threadIdx.x, b = blockIdx.x;   // 64 blocks x 128 float4 of out

    // combined basis (2 elements/thread)
    {
        const float c20 = coeff2[0], c21 = coeff2[1], c22 = coeff2[2], c23 = coeff2[3];
#pragma unroll
        for (int j = 0; j < 2; ++j) {
            const int i = tid + j * 256;
            w2csh[i] = c20 * bases2[i]        + c21 * bases2[512 + i] +
                       c22 * bases2[1024 + i] + c23 * bases2[1536 + i];
        }
    }
    // reduce s1 partials (64 x 32, L2-hot): thread (h=tid&31, g=tid>>5) sums 8 blocks
    {
        const int h = tid & 31, g = tid >> 5;
        float a0 = 0.f, a1 = 0.f;
#pragma unroll
        for (int k = 0; k < 4; ++k) {
            a0 += ws[S1P + (g * 8 + k    ) * HID + h];
            a1 += ws[S1P + (g * 8 + 4 + k) * HID + h];
        }
        red[tid] = a0 + a1;
    }
    __syncthreads();
    if (tid < HID) {
        float t = 0.f;
#pragma unroll
        for (int g = 0; g < 8; ++g) t += red[g * 32 + tid];
        s1sh[tid] = t;
    }
    __syncthreads();
    if (tid < OUTD) {
        float s = 0.f;
#pragma unroll
        for (int h = 0; h < HID; ++h) s += s1sh[h] * w2csh[h * OUTD + tid];
        agg2sh[tid] = bias2[tid] + s;
    }
    __syncthreads();

    // out += agg2 (broadcast over rows): 64 blocks x 128 float4 = 128 KB RMW
    if (tid < 128) {
        const int i = b * 128 + tid;               // float4 index into out
        float4 v = ((float4*)out)[i];
        const int c = (tid & 3) << 2;              // col base of this float4
        v.x += agg2sh[c];     v.y += agg2sh[c + 1];
        v.z += agg2sh[c + 2]; v.w += agg2sh[c + 3];
        ((float4*)out)[i] = v;
    }
}

extern "C" void kernel_launch(void* const* d_in, const int* in_sizes, int n_in,
                              void* d_out, int out_size, void* d_ws, size_t ws_size,
                              hipStream_t stream) {
    const float* x       = (const float*)d_in[0];
    // d_in[1] = adj_matrix: mathematically unused (complete graph w/ self-loops)
    const float* bases1  = (const float*)d_in[2];
    const float* coeff1  = (const float*)d_in[3];
    const float* loop_w1 = (const float*)d_in[4];
    const float* bias1   = (const float*)d_in[5];
    const float* bases2  = (const float*)d_in[6];
    const float* coeff2  = (const float*)d_in[7];
    const float* loop_w2 = (const float*)d_in[8];
    const float* bias2   = (const float*)d_in[9];
    float* out = (float*)d_out;
    float* ws  = (float*)d_ws;

    k1_colsum_x<<<64, 256, 0, stream>>>(x, ws);
    k2_layer1 <<<64, 256, 0, stream>>>(x, bases1, coeff1, loop_w1, bias1, loop_w2, ws, out);
    k3_finish <<<64, 256, 0, stream>>>(bases2, coeff2, bias2, ws, out);
}